// Round 3
// 3203.983 us; speedup vs baseline: 1.0016x; 1.0016x over previous
//
#include <hip/hip_runtime.h>
#include <math.h>

#define HH 512
#define DD 512
#define BB 64
#define SS 256
#define KK 1024
#define CC 5

typedef __attribute__((ext_vector_type(8))) short short8;
typedef __attribute__((ext_vector_type(4))) float float4v;

// ---- workspace layout (bytes) ----  total 101,188,608 B
#define OFF_XEF     0u               // 256 s x 2 sp x 64 b x 512 k shorts = 33.5 MB
#define OFF_HSPL    33554432u        // [2 sp][2 phase][2 dir][64 b][512 k] shorts
#define OFF_FLG     34078720u        // 256 x 4B flags
#define OFF_HIST    34079744u        // 2 x 256 x 512 x 64 fp32 = 67 MB
#define OFF_POOLED  OFF_HSPL         // pooled overlays hspl (dead after recurrence)
#define HSPL_PLANE  131072           // shorts per split plane

__device__ __forceinline__ unsigned f2bf_bits(float f) {
    unsigned u = __builtin_bit_cast(unsigned, f);
    return (u + 0x7fffu + ((u >> 16) & 1u)) >> 16;   // RNE
}
__device__ __forceinline__ float sigm_(float v) {
    return 1.f / (1.f + expf(-v));
}
__device__ __forceinline__ float tanh_(float v) {
    return tanhf(v);
}

// ---------------------------------------------------------------------------
// Gather embeddings + split hi/lo bf16 into xef[s][sp][b][k].
// ---------------------------------------------------------------------------
__global__ __launch_bounds__(256)
void gather_split_k(const int* __restrict__ x, const float* __restrict__ embed,
                    short* __restrict__ xef)
{
    const int s   = blockIdx.x;
    const int tid = threadIdx.x;
    const int b   = tid & 63;
    const int seg = tid >> 6;            // 4 segs x 128 k
    __shared__ int rows[BB];
    if (tid < BB) rows[tid] = x[tid * SS + s];   // x is [B][S]
    __syncthreads();
    const float* e = embed + (size_t)rows[b] * DD + seg * 128;
    short* oh = xef + ((size_t)(s * 2 + 0) * BB + b) * 512 + seg * 128;
    short* ol = xef + ((size_t)(s * 2 + 1) * BB + b) * 512 + seg * 128;
    for (int k0 = 0; k0 < 128; k0 += 8) {
        const float4 a = *(const float4*)(e + k0);
        const float4 c = *(const float4*)(e + k0 + 4);
        const float ev[8] = {a.x, a.y, a.z, a.w, c.x, c.y, c.z, c.w};
        short8 vh, vl;
        #pragma unroll
        for (int j = 0; j < 8; ++j) {
            const unsigned hib = f2bf_bits(ev[j]);
            const float hif = __builtin_bit_cast(float, hib << 16);
            const unsigned lob = f2bf_bits(ev[j] - hif);
            vh[j] = (short)hib;
            vl[j] = (short)lob;
        }
        *(short8*)(oh + k0) = vh;
        *(short8*)(ol + k0) = vl;
    }
}

// ---------------------------------------------------------------------------
__global__ __launch_bounds__(256)
void zero_k(unsigned* __restrict__ base, int ndw)
{
    int i = blockIdx.x * 256 + threadIdx.x;
    const int stride = gridDim.x * 256;
    for (; i < ndw; i += stride) base[i] = 0u;
}

// ---------------------------------------------------------------------------
// Cooperative recurrence: 256 WGs x 256 thr (1 WG/CU). R10 = EXACT R0-proven
// body (R1/R2's register-staging restructure failed deterministically with a
// mechanism we could not identify — reverted wholesale). Single change vs R0:
// s_sleep(32) backoff in the flag spin loop. This cannot alter any computed
// value (pure poll timing); it attacks MALL same-line contention from 512
// waves/dir hammering the 4 flag cache lines with agent-scope loads, which
// queues the producer's own flag store behind the poll backlog.
// ---------------------------------------------------------------------------
__global__ void __launch_bounds__(256, 1)
bilstm_recur_k(const short* __restrict__ xef,
               const float* __restrict__ fwd_W, const float* __restrict__ bwd_W,
               const float* __restrict__ fwd_b, const float* __restrict__ bwd_b,
               short* __restrict__ hspl, float* __restrict__ hist,
               unsigned* __restrict__ flg)
{
    extern __shared__ char smem[];
    short8* wlds = (short8*)smem;                          // 64 KB W fragments
    float*  ex   = (float*)(smem + 65536);                 // 4 KB exchange
    unsigned short* stg = (unsigned short*)(smem + 69632); // 1 KB publish stage

    const int w      = blockIdx.x;
    const int dir    = w >> 7;
    const int wlocal = w & 127;
    const int h0     = wlocal << 2;
    const int tid    = threadIdx.x;
    const int lane   = tid & 63;
    const int wv     = __builtin_amdgcn_readfirstlane(tid >> 6);
    const int n0     = wv << 4;
    const int nn     = lane & 15;
    const int quad   = lane >> 4;

    // ---- pack this WG's W fragments straight into LDS (bit-identical to
    //      wpack_k: f2bf_bits split of W[(g*H+h0+hh)][kt*32+quad*8+j]) ----
    {
        const float* W = dir ? bwd_W : fwd_W;
        const int m  = lane & 15;
        const int g  = m >> 2;
        const int hh = m & 3;
        const float* wrow = W + ((size_t)g * HH + h0 + hh) * KK + quad * 8;
        for (int kk = 0; kk < 8; ++kk) {
            const int kt = wv * 8 + kk;          // 4 waves x 8 = 32 kt
            const float4 a  = *(const float4*)(wrow + kt * 32);
            const float4 c4 = *(const float4*)(wrow + kt * 32 + 4);
            const float ev[8] = {a.x, a.y, a.z, a.w, c4.x, c4.y, c4.z, c4.w};
            short8 vh, vl;
            #pragma unroll
            for (int j = 0; j < 8; ++j) {
                const unsigned hib = f2bf_bits(ev[j]);
                const float hif = __builtin_bit_cast(float, hib << 16);
                const unsigned lob = f2bf_bits(ev[j] - hif);
                vh[j] = (short)hib;
                vl[j] = (short)lob;
            }
            wlds[(0 * 32 + kt) * 64 + lane] = vh;
            wlds[(1 * 32 + kt) * 64 + lane] = vl;
        }
    }
    __syncthreads();

    const float* bi = dir ? bwd_b : fwd_b;
    const float4 biasv = *(const float4*)(bi + quad * HH + h0);
    const float bias_arr[4] = {biasv.x, biasv.y, biasv.z, biasv.w};

    unsigned* myflg = flg + dir * 128;
    float* exw = ex + wv * 256;
    const int b = n0 + nn;
    const int h = h0 + quad;

    for (int t = 0; t < SS; ++t) {
        const int s = dir ? (SS - 1 - t) : t;
        const int p = t & 1;

        float4v acc = {0.f, 0.f, 0.f, 0.f};

        // ---------- x-part: contiguous fragment loads from xef ----------
        {
            const short8* xh8 = (const short8*)(xef +
                ((size_t)(s * 2 + 0) * BB + b) * 512 + quad * 8);
            const short8* xl8 = (const short8*)(xef +
                ((size_t)(s * 2 + 1) * BB + b) * 512 + quad * 8);
            #pragma unroll
            for (int kt = 0; kt < 16; ++kt) {
                const short8 xh  = xh8[kt * 4];
                const short8 xl  = xl8[kt * 4];
                const short8 whi = wlds[(0 * 32 + kt) * 64 + lane];
                const short8 wlo = wlds[(1 * 32 + kt) * 64 + lane];
                acc = __builtin_amdgcn_mfma_f32_16x16x32_bf16(whi, xh, acc, 0, 0, 0);
                acc = __builtin_amdgcn_mfma_f32_16x16x32_bf16(whi, xl, acc, 0, 0, 0);
                acc = __builtin_amdgcn_mfma_f32_16x16x32_bf16(wlo, xh, acc, 0, 0, 0);
            }
        }

        // ---------- wait: all WGs of this dir finished step t-1 ----------
        // R10: identical protocol to R0 (same wave observes flags then loads
        // h), with s_sleep backoff between polls to cut MALL flag-line
        // contention. s_sleep(32) ~= 2048 clk ~= 0.85us.
        if (t > 0) {
            const unsigned tgt = (unsigned)t;
            unsigned va, vb;
            va = __hip_atomic_load(myflg + lane, __ATOMIC_RELAXED,
                                   __HIP_MEMORY_SCOPE_AGENT);
            vb = __hip_atomic_load(myflg + 64 + lane, __ATOMIC_RELAXED,
                                   __HIP_MEMORY_SCOPE_AGENT);
            while (__any(va < tgt || vb < tgt)) {
                __builtin_amdgcn_s_sleep(32);
                va = __hip_atomic_load(myflg + lane, __ATOMIC_RELAXED,
                                       __HIP_MEMORY_SCOPE_AGENT);
                vb = __hip_atomic_load(myflg + 64 + lane, __ATOMIC_RELAXED,
                                       __HIP_MEMORY_SCOPE_AGENT);
            }
            asm volatile("" ::: "memory");
        }

        // ---------- h-part: agent-scope 8B loads ----------
        {
            const size_t zrow = ((size_t)(p * 2 + dir) * BB + b) * HH + quad * 8;
            const unsigned long long* zhq = (const unsigned long long*)(hspl + zrow);
            const unsigned long long* zlq =
                (const unsigned long long*)(hspl + HSPL_PLANE + zrow);
            #pragma unroll
            for (int kt = 0; kt < 16; ++kt) {
                union { unsigned long long q[2]; short8 v; } uh, ul;
                uh.q[0] = __hip_atomic_load(zhq + kt * 8 + 0, __ATOMIC_RELAXED,
                                            __HIP_MEMORY_SCOPE_AGENT);
                uh.q[1] = __hip_atomic_load(zhq + kt * 8 + 1, __ATOMIC_RELAXED,
                                            __HIP_MEMORY_SCOPE_AGENT);
                ul.q[0] = __hip_atomic_load(zlq + kt * 8 + 0, __ATOMIC_RELAXED,
                                            __HIP_MEMORY_SCOPE_AGENT);
                ul.q[1] = __hip_atomic_load(zlq + kt * 8 + 1, __ATOMIC_RELAXED,
                                            __HIP_MEMORY_SCOPE_AGENT);
                const short8 whi = wlds[(0 * 32 + 16 + kt) * 64 + lane];
                const short8 wlo = wlds[(1 * 32 + 16 + kt) * 64 + lane];
                acc = __builtin_amdgcn_mfma_f32_16x16x32_bf16(whi, uh.v, acc, 0, 0, 0);
                acc = __builtin_amdgcn_mfma_f32_16x16x32_bf16(whi, ul.v, acc, 0, 0, 0);
                acc = __builtin_amdgcn_mfma_f32_16x16x32_bf16(wlo, uh.v, acc, 0, 0, 0);
            }
        }

        // ---------- bias + per-wave exchange ----------
        #pragma unroll
        for (int r2 = 0; r2 < 4; ++r2)
            exw[(quad * 4 + r2) * 16 + nn] = acc[r2] + bias_arr[r2];
        float pg[4];
        #pragma unroll
        for (int g_ = 0; g_ < 4; ++g_)
            pg[g_] = exw[(g_ * 4 + quad) * 16 + nn];

        const float f_  = sigm_(pg[0]);
        const float i_  = sigm_(pg[1]);
        const float ct  = tanh_(pg[2]);
        const float o_  = sigm_(pg[3]);
        const float c_  = (f_ + i_) * ct;      // faithful: prev cell unused
        const float hn  = o_ * tanh_(c_);

        const unsigned hib = f2bf_bits(hn);
        const float hif = __builtin_bit_cast(float, hib << 16);
        const unsigned lob = f2bf_bits(hn - hif);
        stg[(0 * 4 + quad) * 64 + b] = (unsigned short)hib;
        stg[(1 * 4 + quad) * 64 + b] = (unsigned short)lob;
        hist[(((size_t)dir * SS + s) * HH + h) * BB + b] = hn;
        __syncthreads();

        // ---------- publish: packed dword write-through stores ----------
        {
            const int plane = tid >> 7;          // 0 hi, 1 lo
            const int d     = tid & 127;
            const int pb    = d >> 1;
            const int pair  = d & 1;
            const unsigned v0 = stg[(plane * 4 + pair * 2 + 0) * 64 + pb];
            const unsigned v1 = stg[(plane * 4 + pair * 2 + 1) * 64 + pb];
            const unsigned val = v0 | (v1 << 16);
            const size_t soff = ((size_t)((p ^ 1) * 2 + dir) * BB + pb) * HH
                                + h0 + pair * 2;
            unsigned* dst = (unsigned*)(hspl + (size_t)plane * HSPL_PLANE + soff);
            __hip_atomic_store(dst, val, __ATOMIC_RELAXED,
                               __HIP_MEMORY_SCOPE_AGENT);
        }
        asm volatile("s_waitcnt vmcnt(0)" ::: "memory");
        __syncthreads();
        if (tid == 0)
            __hip_atomic_store(myflg + wlocal, (unsigned)(t + 1),
                               __ATOMIC_RELAXED, __HIP_MEMORY_SCOPE_AGENT);
    }
}

// ---------------------------------------------------------------------------
__global__ __launch_bounds__(256)
void pool_k(const float* __restrict__ hist, float* __restrict__ pooled)
{
    const int i = blockIdx.x * 256 + threadIdx.x;   // i = h*64 + b
    float m = -2.0f;
    for (int s = 0; s < SS; ++s) {
        const float a = hist[(size_t)s * (HH * BB) + i];
        const float c = hist[(size_t)(SS + s) * (HH * BB) + i];
        m = fmaxf(m, tanhf(a * c));
    }
    pooled[i] = m;
}

__global__ __launch_bounds__(256)
void outgemm_k(const float* __restrict__ pooled, const float* __restrict__ Wout,
               const float* __restrict__ bout, float* __restrict__ out)
{
    const int c   = blockIdx.x;
    const int tid = threadIdx.x;
    const int b   = tid & 63;
    const int q   = __builtin_amdgcn_readfirstlane(tid >> 6);
    float p = 0.0f;
    for (int j = 0; j < 128; ++j) {
        const int h = q * 128 + j;
        p = fmaf(pooled[(size_t)h * BB + b], Wout[c * HH + h], p);
    }
    __shared__ float red[4][BB];
    red[q][b] = p;
    __syncthreads();
    if (tid < BB)
        out[tid * CC + c] = red[0][tid] + red[1][tid] + red[2][tid] + red[3][tid] + bout[c];
}

// ---------------------------------------------------------------------------
extern "C" void kernel_launch(void* const* d_in, const int* in_sizes, int n_in,
                              void* d_out, int out_size, void* d_ws, size_t ws_size,
                              hipStream_t stream)
{
    const int*   x     = (const int*)d_in[0];
    const float* embed = (const float*)d_in[1];
    const float* fwd_W = (const float*)d_in[2];
    const float* fwd_b = (const float*)d_in[3];
    const float* bwd_W = (const float*)d_in[4];
    const float* bwd_b = (const float*)d_in[5];
    const float* Wout  = (const float*)d_in[6];
    const float* bout  = (const float*)d_in[7];
    float* out = (float*)d_out;

    char* wsb = (char*)d_ws;
    short*    xef    = (short*)(wsb + OFF_XEF);
    short*    hspl   = (short*)(wsb + OFF_HSPL);
    unsigned* flg    = (unsigned*)(wsb + OFF_FLG);
    float*    hist   = (float*)(wsb + OFF_HIST);
    float*    pooled = (float*)(wsb + OFF_POOLED);   // overlays hspl (dead)

    gather_split_k<<<SS, 256, 0, stream>>>(x, embed, xef);
    zero_k<<<512, 256, 0, stream>>>((unsigned*)(wsb + OFF_HSPL),
                                    (int)((524288 + 1024) / 4));

    hipFuncSetAttribute((const void*)bilstm_recur_k,
                        hipFuncAttributeMaxDynamicSharedMemorySize, 70656);
    void* args[] = {(void*)&xef, (void*)&fwd_W, (void*)&bwd_W,
                    (void*)&fwd_b, (void*)&bwd_b,
                    (void*)&hspl, (void*)&hist, (void*)&flg};
    hipLaunchCooperativeKernel((void*)bilstm_recur_k, dim3(256), dim3(256),
                               args, 70656, stream);

    pool_k<<<128, 256, 0, stream>>>(hist, pooled);
    outgemm_k<<<CC, 256, 0, stream>>>(pooled, Wout, bout, out);
}

// Round 4
// 3198.079 us; speedup vs baseline: 1.0034x; 1.0018x over previous
//
#include <hip/hip_runtime.h>
#include <math.h>

#define HH 512
#define DD 512
#define BB 64
#define SS 256
#define KK 1024
#define CC 5

typedef __attribute__((ext_vector_type(8))) short short8;
typedef __attribute__((ext_vector_type(4))) float float4v;

// ---- workspace layout (bytes) ----  total 101,188,608 B
#define OFF_XEF     0u               // 256 s x 2 sp x 64 b x 512 k shorts = 33.5 MB
#define OFF_HSPL    33554432u        // [2 sp][2 phase][2 dir][64 b][512 k] shorts
#define OFF_FLG     34078720u        // 256 x 4B flags
#define OFF_HIST    34079744u        // 2 x 256 x 512 x 64 fp32 = 67 MB
#define OFF_POOLED  OFF_HSPL         // pooled overlays hspl (dead after recurrence)
#define HSPL_PLANE  131072           // shorts per split plane

__device__ __forceinline__ unsigned f2bf_bits(float f) {
    unsigned u = __builtin_bit_cast(unsigned, f);
    return (u + 0x7fffu + ((u >> 16) & 1u)) >> 16;   // RNE
}
__device__ __forceinline__ float sigm_(float v) {
    return 1.f / (1.f + expf(-v));
}
__device__ __forceinline__ float tanh_(float v) {
    return tanhf(v);
}

// ---------------------------------------------------------------------------
// Gather embeddings + split hi/lo bf16 into xef[s][sp][b][k].
// ---------------------------------------------------------------------------
__global__ __launch_bounds__(256)
void gather_split_k(const int* __restrict__ x, const float* __restrict__ embed,
                    short* __restrict__ xef)
{
    const int s   = blockIdx.x;
    const int tid = threadIdx.x;
    const int b   = tid & 63;
    const int seg = tid >> 6;            // 4 segs x 128 k
    __shared__ int rows[BB];
    if (tid < BB) rows[tid] = x[tid * SS + s];   // x is [B][S]
    __syncthreads();
    const float* e = embed + (size_t)rows[b] * DD + seg * 128;
    short* oh = xef + ((size_t)(s * 2 + 0) * BB + b) * 512 + seg * 128;
    short* ol = xef + ((size_t)(s * 2 + 1) * BB + b) * 512 + seg * 128;
    for (int k0 = 0; k0 < 128; k0 += 8) {
        const float4 a = *(const float4*)(e + k0);
        const float4 c = *(const float4*)(e + k0 + 4);
        const float ev[8] = {a.x, a.y, a.z, a.w, c.x, c.y, c.z, c.w};
        short8 vh, vl;
        #pragma unroll
        for (int j = 0; j < 8; ++j) {
            const unsigned hib = f2bf_bits(ev[j]);
            const float hif = __builtin_bit_cast(float, hib << 16);
            const unsigned lob = f2bf_bits(ev[j] - hif);
            vh[j] = (short)hib;
            vl[j] = (short)lob;
        }
        *(short8*)(oh + k0) = vh;
        *(short8*)(ol + k0) = vl;
    }
}

// ---------------------------------------------------------------------------
__global__ __launch_bounds__(256)
void zero_k(unsigned* __restrict__ base, int ndw)
{
    int i = blockIdx.x * 256 + threadIdx.x;
    const int stride = gridDim.x * 256;
    for (; i < ndw; i += stride) base[i] = 0u;
}

// ---------------------------------------------------------------------------
// Cooperative recurrence: 256 WGs x 256 thr (1 WG/CU). R11 = R3-proven body
// with ONE change: depth-2 software pipeline in the h-part (named scalars
// only, +16 VGPRs, no arrays/spill — the minimal form of R1's idea). Issue
// group kt+1's 4 agent loads BEFORE computing group kt, halving the exposed
// MALL round-trip count (16 -> ~8 per step). Everything else byte-identical
// to R3 (passed, 3204 us).
// ---------------------------------------------------------------------------
__global__ void __launch_bounds__(256, 1)
bilstm_recur_k(const short* __restrict__ xef,
               const float* __restrict__ fwd_W, const float* __restrict__ bwd_W,
               const float* __restrict__ fwd_b, const float* __restrict__ bwd_b,
               short* __restrict__ hspl, float* __restrict__ hist,
               unsigned* __restrict__ flg)
{
    extern __shared__ char smem[];
    short8* wlds = (short8*)smem;                          // 64 KB W fragments
    float*  ex   = (float*)(smem + 65536);                 // 4 KB exchange
    unsigned short* stg = (unsigned short*)(smem + 69632); // 1 KB publish stage

    const int w      = blockIdx.x;
    const int dir    = w >> 7;
    const int wlocal = w & 127;
    const int h0     = wlocal << 2;
    const int tid    = threadIdx.x;
    const int lane   = tid & 63;
    const int wv     = __builtin_amdgcn_readfirstlane(tid >> 6);
    const int n0     = wv << 4;
    const int nn     = lane & 15;
    const int quad   = lane >> 4;

    // ---- pack this WG's W fragments straight into LDS (bit-identical to
    //      wpack_k: f2bf_bits split of W[(g*H+h0+hh)][kt*32+quad*8+j]) ----
    {
        const float* W = dir ? bwd_W : fwd_W;
        const int m  = lane & 15;
        const int g  = m >> 2;
        const int hh = m & 3;
        const float* wrow = W + ((size_t)g * HH + h0 + hh) * KK + quad * 8;
        for (int kk = 0; kk < 8; ++kk) {
            const int kt = wv * 8 + kk;          // 4 waves x 8 = 32 kt
            const float4 a  = *(const float4*)(wrow + kt * 32);
            const float4 c4 = *(const float4*)(wrow + kt * 32 + 4);
            const float ev[8] = {a.x, a.y, a.z, a.w, c4.x, c4.y, c4.z, c4.w};
            short8 vh, vl;
            #pragma unroll
            for (int j = 0; j < 8; ++j) {
                const unsigned hib = f2bf_bits(ev[j]);
                const float hif = __builtin_bit_cast(float, hib << 16);
                const unsigned lob = f2bf_bits(ev[j] - hif);
                vh[j] = (short)hib;
                vl[j] = (short)lob;
            }
            wlds[(0 * 32 + kt) * 64 + lane] = vh;
            wlds[(1 * 32 + kt) * 64 + lane] = vl;
        }
    }
    __syncthreads();

    const float* bi = dir ? bwd_b : fwd_b;
    const float4 biasv = *(const float4*)(bi + quad * HH + h0);
    const float bias_arr[4] = {biasv.x, biasv.y, biasv.z, biasv.w};

    unsigned* myflg = flg + dir * 128;
    float* exw = ex + wv * 256;
    const int b = n0 + nn;
    const int h = h0 + quad;

    for (int t = 0; t < SS; ++t) {
        const int s = dir ? (SS - 1 - t) : t;
        const int p = t & 1;

        float4v acc = {0.f, 0.f, 0.f, 0.f};

        // ---------- x-part: contiguous fragment loads from xef ----------
        {
            const short8* xh8 = (const short8*)(xef +
                ((size_t)(s * 2 + 0) * BB + b) * 512 + quad * 8);
            const short8* xl8 = (const short8*)(xef +
                ((size_t)(s * 2 + 1) * BB + b) * 512 + quad * 8);
            #pragma unroll
            for (int kt = 0; kt < 16; ++kt) {
                const short8 xh  = xh8[kt * 4];
                const short8 xl  = xl8[kt * 4];
                const short8 whi = wlds[(0 * 32 + kt) * 64 + lane];
                const short8 wlo = wlds[(1 * 32 + kt) * 64 + lane];
                acc = __builtin_amdgcn_mfma_f32_16x16x32_bf16(whi, xh, acc, 0, 0, 0);
                acc = __builtin_amdgcn_mfma_f32_16x16x32_bf16(whi, xl, acc, 0, 0, 0);
                acc = __builtin_amdgcn_mfma_f32_16x16x32_bf16(wlo, xh, acc, 0, 0, 0);
            }
        }

        // ---------- wait: all WGs of this dir finished step t-1 ----------
        if (t > 0) {
            const unsigned tgt = (unsigned)t;
            unsigned va, vb;
            va = __hip_atomic_load(myflg + lane, __ATOMIC_RELAXED,
                                   __HIP_MEMORY_SCOPE_AGENT);
            vb = __hip_atomic_load(myflg + 64 + lane, __ATOMIC_RELAXED,
                                   __HIP_MEMORY_SCOPE_AGENT);
            while (__any(va < tgt || vb < tgt)) {
                __builtin_amdgcn_s_sleep(32);
                va = __hip_atomic_load(myflg + lane, __ATOMIC_RELAXED,
                                       __HIP_MEMORY_SCOPE_AGENT);
                vb = __hip_atomic_load(myflg + 64 + lane, __ATOMIC_RELAXED,
                                       __HIP_MEMORY_SCOPE_AGENT);
            }
            asm volatile("" ::: "memory");
        }

        // ---------- h-part: agent-scope 8B loads, depth-2 pipeline ----------
        {
            const size_t zrow = ((size_t)(p * 2 + dir) * BB + b) * HH + quad * 8;
            const unsigned long long* zhq = (const unsigned long long*)(hspl + zrow);
            const unsigned long long* zlq =
                (const unsigned long long*)(hspl + HSPL_PLANE + zrow);

#define LD_GRP(d0, d1, d2, d3, KT)                                            \
            d0 = __hip_atomic_load(zhq + (KT) * 8 + 0, __ATOMIC_RELAXED,      \
                                   __HIP_MEMORY_SCOPE_AGENT);                 \
            d1 = __hip_atomic_load(zhq + (KT) * 8 + 1, __ATOMIC_RELAXED,      \
                                   __HIP_MEMORY_SCOPE_AGENT);                 \
            d2 = __hip_atomic_load(zlq + (KT) * 8 + 0, __ATOMIC_RELAXED,      \
                                   __HIP_MEMORY_SCOPE_AGENT);                 \
            d3 = __hip_atomic_load(zlq + (KT) * 8 + 1, __ATOMIC_RELAXED,      \
                                   __HIP_MEMORY_SCOPE_AGENT);

#define MM_GRP(s0, s1, s2, s3, KT)                                            \
            {                                                                 \
                union { unsigned long long q[2]; short8 v; } uh, ul;          \
                uh.q[0] = s0; uh.q[1] = s1;                                   \
                ul.q[0] = s2; ul.q[1] = s3;                                   \
                const short8 whi = wlds[(0 * 32 + 16 + (KT)) * 64 + lane];    \
                const short8 wlo = wlds[(1 * 32 + 16 + (KT)) * 64 + lane];    \
                acc = __builtin_amdgcn_mfma_f32_16x16x32_bf16(whi, uh.v, acc, 0, 0, 0); \
                acc = __builtin_amdgcn_mfma_f32_16x16x32_bf16(whi, ul.v, acc, 0, 0, 0); \
                acc = __builtin_amdgcn_mfma_f32_16x16x32_bf16(wlo, uh.v, acc, 0, 0, 0); \
            }

            unsigned long long a0, a1, a2, a3, b0, b1, b2, b3;
            LD_GRP(a0, a1, a2, a3, 0)
            #pragma unroll
            for (int kt = 0; kt < 16; kt += 2) {
                LD_GRP(b0, b1, b2, b3, kt + 1)
                MM_GRP(a0, a1, a2, a3, kt)
                if (kt + 2 < 16) {
                    LD_GRP(a0, a1, a2, a3, kt + 2)
                }
                MM_GRP(b0, b1, b2, b3, kt + 1)
            }
#undef LD_GRP
#undef MM_GRP
        }

        // ---------- bias + per-wave exchange ----------
        #pragma unroll
        for (int r2 = 0; r2 < 4; ++r2)
            exw[(quad * 4 + r2) * 16 + nn] = acc[r2] + bias_arr[r2];
        float pg[4];
        #pragma unroll
        for (int g_ = 0; g_ < 4; ++g_)
            pg[g_] = exw[(g_ * 4 + quad) * 16 + nn];

        const float f_  = sigm_(pg[0]);
        const float i_  = sigm_(pg[1]);
        const float ct  = tanh_(pg[2]);
        const float o_  = sigm_(pg[3]);
        const float c_  = (f_ + i_) * ct;      // faithful: prev cell unused
        const float hn  = o_ * tanh_(c_);

        const unsigned hib = f2bf_bits(hn);
        const float hif = __builtin_bit_cast(float, hib << 16);
        const unsigned lob = f2bf_bits(hn - hif);
        stg[(0 * 4 + quad) * 64 + b] = (unsigned short)hib;
        stg[(1 * 4 + quad) * 64 + b] = (unsigned short)lob;
        hist[(((size_t)dir * SS + s) * HH + h) * BB + b] = hn;
        __syncthreads();

        // ---------- publish: packed dword write-through stores ----------
        {
            const int plane = tid >> 7;          // 0 hi, 1 lo
            const int d     = tid & 127;
            const int pb    = d >> 1;
            const int pair  = d & 1;
            const unsigned v0 = stg[(plane * 4 + pair * 2 + 0) * 64 + pb];
            const unsigned v1 = stg[(plane * 4 + pair * 2 + 1) * 64 + pb];
            const unsigned val = v0 | (v1 << 16);
            const size_t soff = ((size_t)((p ^ 1) * 2 + dir) * BB + pb) * HH
                                + h0 + pair * 2;
            unsigned* dst = (unsigned*)(hspl + (size_t)plane * HSPL_PLANE + soff);
            __hip_atomic_store(dst, val, __ATOMIC_RELAXED,
                               __HIP_MEMORY_SCOPE_AGENT);
        }
        asm volatile("s_waitcnt vmcnt(0)" ::: "memory");
        __syncthreads();
        if (tid == 0)
            __hip_atomic_store(myflg + wlocal, (unsigned)(t + 1),
                               __ATOMIC_RELAXED, __HIP_MEMORY_SCOPE_AGENT);
    }
}

// ---------------------------------------------------------------------------
__global__ __launch_bounds__(256)
void pool_k(const float* __restrict__ hist, float* __restrict__ pooled)
{
    const int i = blockIdx.x * 256 + threadIdx.x;   // i = h*64 + b
    float m = -2.0f;
    for (int s = 0; s < SS; ++s) {
        const float a = hist[(size_t)s * (HH * BB) + i];
        const float c = hist[(size_t)(SS + s) * (HH * BB) + i];
        m = fmaxf(m, tanhf(a * c));
    }
    pooled[i] = m;
}

__global__ __launch_bounds__(256)
void outgemm_k(const float* __restrict__ pooled, const float* __restrict__ Wout,
               const float* __restrict__ bout, float* __restrict__ out)
{
    const int c   = blockIdx.x;
    const int tid = threadIdx.x;
    const int b   = tid & 63;
    const int q   = __builtin_amdgcn_readfirstlane(tid >> 6);
    float p = 0.0f;
    for (int j = 0; j < 128; ++j) {
        const int h = q * 128 + j;
        p = fmaf(pooled[(size_t)h * BB + b], Wout[c * HH + h], p);
    }
    __shared__ float red[4][BB];
    red[q][b] = p;
    __syncthreads();
    if (tid < BB)
        out[tid * CC + c] = red[0][tid] + red[1][tid] + red[2][tid] + red[3][tid] + bout[c];
}

// ---------------------------------------------------------------------------
extern "C" void kernel_launch(void* const* d_in, const int* in_sizes, int n_in,
                              void* d_out, int out_size, void* d_ws, size_t ws_size,
                              hipStream_t stream)
{
    const int*   x     = (const int*)d_in[0];
    const float* embed = (const float*)d_in[1];
    const float* fwd_W = (const float*)d_in[2];
    const float* fwd_b = (const float*)d_in[3];
    const float* bwd_W = (const float*)d_in[4];
    const float* bwd_b = (const float*)d_in[5];
    const float* Wout  = (const float*)d_in[6];
    const float* bout  = (const float*)d_in[7];
    float* out = (float*)d_out;

    char* wsb = (char*)d_ws;
    short*    xef    = (short*)(wsb + OFF_XEF);
    short*    hspl   = (short*)(wsb + OFF_HSPL);
    unsigned* flg    = (unsigned*)(wsb + OFF_FLG);
    float*    hist   = (float*)(wsb + OFF_HIST);
    float*    pooled = (float*)(wsb + OFF_POOLED);   // overlays hspl (dead)

    gather_split_k<<<SS, 256, 0, stream>>>(x, embed, xef);
    zero_k<<<512, 256, 0, stream>>>((unsigned*)(wsb + OFF_HSPL),
                                    (int)((524288 + 1024) / 4));

    hipFuncSetAttribute((const void*)bilstm_recur_k,
                        hipFuncAttributeMaxDynamicSharedMemorySize, 70656);
    void* args[] = {(void*)&xef, (void*)&fwd_W, (void*)&bwd_W,
                    (void*)&fwd_b, (void*)&bwd_b,
                    (void*)&hspl, (void*)&hist, (void*)&flg};
    hipLaunchCooperativeKernel((void*)bilstm_recur_k, dim3(256), dim3(256),
                               args, 70656, stream);

    pool_k<<<128, 256, 0, stream>>>(hist, pooled);
    outgemm_k<<<CC, 256, 0, stream>>>(pooled, Wout, bout, out);
}